// Round 5
// baseline (153.285 us; speedup 1.0000x reference)
//
#include <hip/hip_runtime.h>
#include <hip/hip_bf16.h>

// N=32 time, 32x32 grid, C=64 (H=4 x D=16), 3x3x3 offsets (M=27), 2 layers.
// R16 = R15 + (a) coalesced prep repack (was ~19us of scalar 256B-stride
// gathers; now per-matrix blocks, float4->LDS->short8 coalesced), (b) macro
// m-loop body (no lambda; R15's WRITE_SIZE 14.7MB hinted scratch), (c) wv
// prefetched one m ahead like wk (full body ~500cy covers L2 latency; R15
// issued wv only ~130cy before use), (d) __launch_bounds__(512,3) ~168-VGPR
// budget for the deeper pipeline (occupancy proven irrelevant: R13 70% occ
// == R11 30% occ == 41us).

typedef short short8_t __attribute__((ext_vector_type(8)));
typedef float floatx16 __attribute__((ext_vector_type(16)));

__device__ __forceinline__ short f2bs(float f) {
    __hip_bfloat16 h = __float2bfloat16(f);
    return *reinterpret_cast<short*>(&h);
}
__device__ __forceinline__ float bs2f(short s) {
    union { unsigned u; float f; } v;
    v.u = ((unsigned)(unsigned short)s) << 16;
    return v.f;
}
// swizzled halo addressing: rowid in [0,216), 8 chunks of 8 shorts, pitch 64
__device__ __forceinline__ int hn_idx(int rowid, int chunk) {
    return rowid * 64 + ((chunk ^ (rowid & 7)) << 3);
}
// p(lane) + p(lane^32), all lanes (VALU pipe, no DS)
__device__ __forceinline__ float half_sum(float p) {
    float a = p, b = p;
    asm("v_permlane32_swap_b32 %0, %1" : "+v"(a), "+v"(b));
    return a + b;
}

// ---------------- prep: repack weights (coalesced) + BN partial sums ----------------
// blocks 0..109: one matrix each. 110..141: BN partial sums.
__global__ void prep_kernel(const float* __restrict__ Wq, const float* __restrict__ Wk,
                            const float* __restrict__ Wv, short* __restrict__ dst,
                            const float* __restrict__ x, float* __restrict__ sums) {
    if (blockIdx.x < 110) {
        __shared__ float Wf[4096];
        const int mat = blockIdx.x;
        const float* W;
        if (mat < 2)       W = Wq + mat * 4096;
        else if (mat < 56) W = Wk + (mat - 2) * 4096;
        else               W = Wv + (mat - 56) * 4096;
        const float4* W4 = (const float4*)W;
        #pragma unroll
        for (int i = 0; i < 4; ++i) {
            const int idx = threadIdx.x + i * 256;
            *(float4*)&Wf[idx * 4] = W4[idx];
        }
        __syncthreads();
        // out entry t2 = (hp*4+kk)*64 + lane; A[row=hp*32+(lane&31)][k] layout
        #pragma unroll
        for (int u = 0; u < 2; ++u) {
            const int t2 = u * 256 + threadIdx.x;
            const int hp = t2 >> 8, kk = (t2 >> 6) & 3, lane = t2 & 63;
            const int krow = kk * 16 + ((lane >> 5) << 3);
            const int col  = hp * 32 + (lane & 31);
            short8_t v;
            #pragma unroll
            for (int j = 0; j < 8; ++j) v[j] = f2bs(Wf[(krow + j) * 64 + col]);
            *(short8_t*)&dst[(size_t)mat * 4096 + t2 * 8] = v;
        }
    } else {
        int bid = blockIdx.x - 110;
        int t = bid * 256 + threadIdx.x;          // 8192 threads x 3 float4
        const float4* x4 = (const float4*)x;
        float4 v0 = x4[t * 3 + 0], v1 = x4[t * 3 + 1], v2 = x4[t * 3 + 2];
        float vv[6];
        vv[0] = v0.x + v0.w + v1.z + v2.y;
        vv[1] = v0.y + v1.x + v1.w + v2.z;
        vv[2] = v0.z + v1.y + v2.x + v2.w;
        vv[3] = v0.x*v0.x + v0.w*v0.w + v1.z*v1.z + v2.y*v2.y;
        vv[4] = v0.y*v0.y + v1.x*v1.x + v1.w*v1.w + v2.z*v2.z;
        vv[5] = v0.z*v0.z + v1.y*v1.y + v2.x*v2.x + v2.w*v2.w;
        #pragma unroll
        for (int i = 0; i < 6; ++i) {
            #pragma unroll
            for (int off = 1; off < 64; off <<= 1) vv[i] += __shfl_xor(vv[i], off);
        }
        __shared__ float part[4][6];
        if ((threadIdx.x & 63) == 0) {
            #pragma unroll
            for (int i = 0; i < 6; ++i) part[threadIdx.x >> 6][i] = vv[i];
        }
        __syncthreads();
        if (threadIdx.x < 6)
            sums[bid * 8 + threadIdx.x] = part[0][threadIdx.x] + part[1][threadIdx.x] +
                                          part[2][threadIdx.x] + part[3][threadIdx.x];
    }
}

// ---------------- fused attention layer ----------------
// grid (b=16, a=32, nb=2); block 512 = 8 waves; wave = g4*2 + hp;
// hp = headpair (channels hp*32..+31); g4 = m-group: [0,7),[7,14),[14,21),[21,27).
// lane: col = lane&31 -> (ci = col>>4 cell, e = col&15 time row); h5 = lane>>5.
template <bool FIRST>
__global__ __launch_bounds__(512, 3)
void layer_fused(const float* __restrict__ x, const float* __restrict__ sums,
                 const float* __restrict__ W_in, const float* __restrict__ b_in,
                 const short* __restrict__ hbf_in, short* __restrict__ hbf_out,
                 const float* __restrict__ Wout, const float* __restrict__ bout,
                 float* __restrict__ out,
                 const short* __restrict__ wqB, const float* __restrict__ bq,
                 const short* __restrict__ wkB, const float* __restrict__ bk,
                 const short* __restrict__ wvB, const float* __restrict__ bv) {
    __shared__ short HnS[216 * 64];   // 27.6 KB halo; reused for merge + hf
    __shared__ float BiasS[3456];     // 13.8 KB: [m][k|v][64ch]
    __shared__ float Waux[256];
    __shared__ float bn6[6];

    const int tid = threadIdx.x;
    const int bb0 = blockIdx.x * 2, a = blockIdx.y, nb = blockIdx.z;

    if (FIRST) {
        if (tid < 3) {
            float s = 0.f, qq = 0.f;
            #pragma unroll
            for (int p = 0; p < 32; ++p) { s += sums[p * 8 + tid]; qq += sums[p * 8 + 3 + tid]; }
            float mean = s * (1.f / 32768.f);
            float var  = qq * (1.f / 32768.f) - mean * mean;
            bn6[tid]     = mean;
            bn6[3 + tid] = rsqrtf(var + 1e-5f);
        }
        if (tid < 192)      Waux[tid] = W_in[tid];
        else if (tid < 256) Waux[tid] = b_in[tid - 192];
    } else {
        if (tid < 192)      Waux[tid] = Wout[tid];
        else if (tid < 195) Waux[tid] = bout[tid - 192];
    }
    __syncthreads();

    float mean0 = 0, mean1 = 0, mean2 = 0, rs0 = 0, rs1 = 0, rs2 = 0;
    if (FIRST) {
        mean0 = bn6[0]; mean1 = bn6[1]; mean2 = bn6[2];
        rs0 = bn6[3]; rs1 = bn6[4]; rs2 = bn6[5];
    }

    // ---- stage biases: BiasS[m*128 + (k?0:64) + ch] ----
    for (int id = tid; id < 3456; id += 512) {
        const int half = (id >= 1728) ? 1 : 0;
        const int j = id - half * 1728;
        const float* src = half ? &bv[j] : &bk[j];
        BiasS[((j >> 6) << 7) + (half << 6) + (j & 63)] = *src;
    }

    // ---- stage halo: 216 rows x 8 chunks of 8 bf16 ----
    for (int id = tid; id < 1728; id += 512) {
        int rowid = id >> 3, cc = id & 7;
        int r = rowid % 18;
        int rw = rowid / 18;
        int spa = rw >> 2, jcol = rw & 3;
        int aa = a + spa - 1, bb = bb0 + jcol - 1;
        int n  = nb * 16 + r - 1;
        short8_t v = {0, 0, 0, 0, 0, 0, 0, 0};
        if ((unsigned)n < 32u && (unsigned)aa < 32u && (unsigned)bb < 32u) {
            int cell = (n * 32 + aa) * 32 + bb;
            if (FIRST) {
                float xn0 = (x[cell*3+0] - mean0) * rs0;
                float xn1 = (x[cell*3+1] - mean1) * rs1;
                float xn2 = (x[cell*3+2] - mean2) * rs2;
                #pragma unroll
                for (int j = 0; j < 8; ++j) {
                    int c = cc * 8 + j;
                    float h = Waux[192+c] + xn0*Waux[c] + xn1*Waux[64+c] + xn2*Waux[128+c];
                    v[j] = f2bs(h);
                }
            } else {
                v = *(const short8_t*)&hbf_in[cell * 64 + cc * 8];
            }
        }
        *(short8_t*)&HnS[hn_idx(rowid, cc)] = v;
    }
    __syncthreads();

    const int lane = tid & 63;
    const int wv8  = tid >> 6;
    const int hp   = wv8 & 1;        // headpair
    const int g4   = wv8 >> 1;       // m-group
    const int col  = lane & 31;
    const int e    = col & 15;
    const int ci   = col >> 4;
    const int h5   = lane >> 5;

    // spatial validity
    unsigned amask = 0;
    #pragma unroll
    for (int d = 0; d < 3; ++d) if ((unsigned)(a + d - 1) < 32u) amask |= 1u << d;
    const bool vbL = (unsigned)(bb0 - 1) < 32u;   // jcol 0
    const bool vbR = (unsigned)(bb0 + 2) < 32u;   // jcol 3
    const unsigned vmask = (ci == 0) ? ((vbL ? 1u : 0u) | 2u | 4u)
                                     : (1u | 2u | (vbR ? 4u : 0u));

    const int elane = e + ci * 18;   // per-lane halo-row offset

    // ---- Q projection (center cell per col): 4 chained 32x32x16 MFMAs ----
    floatx16 qv;
    {
        const float* bqp = &bq[hp * 32 + 4 * h5];
        const float4 qa = *(const float4*)&bqp[0];
        const float4 qb = *(const float4*)&bqp[8];
        const float4 qc = *(const float4*)&bqp[16];
        const float4 qd = *(const float4*)&bqp[24];
        qv = floatx16{qa.x,qa.y,qa.z,qa.w, qb.x,qb.y,qb.z,qb.w,
                      qc.x,qc.y,qc.z,qc.w, qd.x,qd.y,qd.z,qd.w};
        const int hrow = (5 + ci) * 18 + e + 1;
        const int hb = hrow * 64, xr = hrow & 7;
        const short8_t b0 = *(const short8_t*)&HnS[hb + (((0 + h5) ^ xr) << 3)];
        const short8_t b1 = *(const short8_t*)&HnS[hb + (((2 + h5) ^ xr) << 3)];
        const short8_t b2 = *(const short8_t*)&HnS[hb + (((4 + h5) ^ xr) << 3)];
        const short8_t b3 = *(const short8_t*)&HnS[hb + (((6 + h5) ^ xr) << 3)];
        const short8_t* wqp = (const short8_t*)&wqB[(hp * 256 + lane) * 8];
        qv = __builtin_amdgcn_mfma_f32_32x32x16_bf16(wqp[0],   b0, qv, 0, 0, 0);
        qv = __builtin_amdgcn_mfma_f32_32x32x16_bf16(wqp[64],  b1, qv, 0, 0, 0);
        qv = __builtin_amdgcn_mfma_f32_32x32x16_bf16(wqp[128], b2, qv, 0, 0, 0);
        qv = __builtin_amdgcn_mfma_f32_32x32x16_bf16(wqp[192], b3, qv, 0, 0, 0);
    }

    // ---- fused K/V pass, branch-free, wk AND wv software-pipelined depth 1 ----
    floatx16 o = {0,0,0,0, 0,0,0,0, 0,0,0,0, 0,0,0,0};
    float ssA = 0.f, ssB = 0.f;

    const int mstart = g4 * 7;
    const int mend   = (g4 == 3) ? 27 : mstart + 7;

    const short* wkBase = wkB + hp * 2048 + lane * 8;
    const short* wvBase = wvB + hp * 2048 + lane * 8;

    short8_t wkP0, wkP1, wkP2, wkP3, wvP0, wvP1, wvP2, wvP3;
    short8_t wkQ0, wkQ1, wkQ2, wkQ3, wvQ0, wvQ1, wvQ2, wvQ3;
    wkP0 = *(const short8_t*)&wkBase[mstart * 4096 + 0];
    wkP1 = *(const short8_t*)&wkBase[mstart * 4096 + 512];
    wkP2 = *(const short8_t*)&wkBase[mstart * 4096 + 1024];
    wkP3 = *(const short8_t*)&wkBase[mstart * 4096 + 1536];
    wvP0 = *(const short8_t*)&wvBase[mstart * 4096 + 0];
    wvP1 = *(const short8_t*)&wvBase[mstart * 4096 + 512];
    wvP2 = *(const short8_t*)&wvBase[mstart * 4096 + 1024];
    wvP3 = *(const short8_t*)&wvBase[mstart * 4096 + 1536];

#define KV_BODY(WKC0,WKC1,WKC2,WKC3, WVC0,WVC1,WVC2,WVC3,                          \
                WKN0,WKN1,WKN2,WKN3, WVN0,WVN1,WVN2,WVN3, MV)                      \
    {                                                                              \
        const int m_  = (MV);                                                      \
        const int mn_ = (m_ + 1 < mend) ? m_ + 1 : m_;                             \
        const int t_  = (m_ * 57) >> 9;                                            \
        const int sp_ = m_ - 9 * t_;                                               \
        const int di_ = (sp_ * 11) >> 5;                                           \
        const int dj_ = sp_ - 3 * di_;                                             \
        const int hrow_ = (di_ * 4 + dj_) * 18 + t_ + elane;                       \
        const int hb_ = hrow_ * 64, xr_ = hrow_ & 7;                               \
        const short8_t b0_ = *(const short8_t*)&HnS[hb_ + (((0 + h5) ^ xr_) << 3)];\
        const short8_t b1_ = *(const short8_t*)&HnS[hb_ + (((2 + h5) ^ xr_) << 3)];\
        const short8_t b2_ = *(const short8_t*)&HnS[hb_ + (((4 + h5) ^ xr_) << 3)];\
        const short8_t b3_ = *(const short8_t*)&HnS[hb_ + (((6 + h5) ^ xr_) << 3)];\
        const float* bks_ = &BiasS[(m_ << 7) + (hp << 5) + (h5 << 2)];             \
        const float4 ka_ = *(const float4*)&bks_[0];                               \
        const float4 kb_ = *(const float4*)&bks_[8];                               \
        const float4 kc_ = *(const float4*)&bks_[16];                              \
        const float4 kd_ = *(const float4*)&bks_[24];                              \
        const float4 va0_ = *(const float4*)&bks_[64];                             \
        const float4 va1_ = *(const float4*)&bks_[72];                             \
        const float4 va2_ = *(const float4*)&bks_[80];                             \
        const float4 va3_ = *(const float4*)&bks_[88];                             \
        WKN0 = *(const short8_t*)&wkBase[mn_ * 4096 + 0];                          \
        WKN1 = *(const short8_t*)&wkBase[mn_ * 4096 + 512];                        \
        WKN2 = *(const short8_t*)&wkBase[mn_ * 4096 + 1024];                       \
        WKN3 = *(const short8_t*)&wkBase[mn_ * 4096 + 1536];                       \
        WVN0 = *(const short8_t*)&wvBase[mn_ * 4096 + 0];                          \
        WVN1 = *(const short8_t*)&wvBase[mn_ * 4096 + 512];                        \
        WVN2 = *(const short8_t*)&wvBase[mn_ * 4096 + 1024];                       \
        WVN3 = *(const short8_t*)&wvBase[mn_ * 4096 + 1536];                       \
        floatx16 kacc_ = floatx16{ka_.x,ka_.y,ka_.z,ka_.w, kb_.x,kb_.y,kb_.z,kb_.w,\
                                  kc_.x,kc_.y,kc_.z,kc_.w, kd_.x,kd_.y,kd_.z,kd_.w};\
        kacc_ = __builtin_amdgcn_mfma_f32_32x32x16_bf16(WKC0, b0_, kacc_, 0, 0, 0);\
        kacc_ = __builtin_amdgcn_mfma_f32_32x32x16_bf16(WKC1, b1_, kacc_, 0, 0, 0);\
        kacc_ = __builtin_amdgcn_mfma_f32_32x32x16_bf16(WKC2, b2_, kacc_, 0, 0, 0);\
        kacc_ = __builtin_amdgcn_mfma_f32_32x32x16_bf16(WKC3, b3_, kacc_, 0, 0, 0);\
        floatx16 vacc_ = floatx16{va0_.x,va0_.y,va0_.z,va0_.w,                     \
                                  va1_.x,va1_.y,va1_.z,va1_.w,                     \
                                  va2_.x,va2_.y,va2_.z,va2_.w,                     \
                                  va3_.x,va3_.y,va3_.z,va3_.w};                    \
        vacc_ = __builtin_amdgcn_mfma_f32_32x32x16_bf16(WVC0, b0_, vacc_, 0, 0, 0);\
        vacc_ = __builtin_amdgcn_mfma_f32_32x32x16_bf16(WVC1, b1_, vacc_, 0, 0, 0);\
        vacc_ = __builtin_amdgcn_mfma_f32_32x32x16_bf16(WVC2, b2_, vacc_, 0, 0, 0);\
        vacc_ = __builtin_amdgcn_mfma_f32_32x32x16_bf16(WVC3, b3_, vacc_, 0, 0, 0);\
        float pA_ = kacc_[0] * qv[0];                                              \
        _Pragma("unroll")                                                          \
        for (int r = 1; r < 8; ++r) pA_ += kacc_[r] * qv[r];                       \
        float pB_ = kacc_[8] * qv[8];                                              \
        _Pragma("unroll")                                                          \
        for (int r = 9; r < 16; ++r) pB_ += kacc_[r] * qv[r];                      \
        pA_ = half_sum(pA_);                                                       \
        pB_ = half_sum(pB_);                                                       \
        const float mf_ = (float)(((amask >> di_) & (vmask >> dj_)) & 1u);         \
        const float wA_ = __expf(pA_) * mf_;                                       \
        const float wB_ = __expf(pB_) * mf_;                                       \
        ssA += wA_; ssB += wB_;                                                    \
        _Pragma("unroll")                                                          \
        for (int r = 0; r < 8; ++r)  o[r] += wA_ * vacc_[r];                       \
        _Pragma("unroll")                                                          \
        for (int r = 8; r < 16; ++r) o[r] += wB_ * vacc_[r];                       \
    }

    for (int m = mstart; m < mend; m += 2) {
        KV_BODY(wkP0,wkP1,wkP2,wkP3, wvP0,wvP1,wvP2,wvP3,
                wkQ0,wkQ1,wkQ2,wkQ3, wvQ0,wvQ1,wvQ2,wvQ3, m)
        if (m + 1 < mend)
        KV_BODY(wkQ0,wkQ1,wkQ2,wkQ3, wvQ0,wvQ1,wvQ2,wvQ3,
                wkP0,wkP1,wkP2,wkP3, wvP0,wvP1,wvP2,wvP3, m + 1)
    }
#undef KV_BODY

    // ---- 4-way merge across m-groups: two pairwise LDS rounds ----
    __syncthreads();
    float* stbuf = (float*)HnS;            // [wid][lane][20], 16B-aligned pitch
    if (g4 >= 2) {
        float* d = &stbuf[(((g4 - 2) * 2 + hp) * 64 + lane) * 20];
        *(float4*)&d[0]  = make_float4(o[0],  o[1],  o[2],  o[3]);
        *(float4*)&d[4]  = make_float4(o[4],  o[5],  o[6],  o[7]);
        *(float4*)&d[8]  = make_float4(o[8],  o[9],  o[10], o[11]);
        *(float4*)&d[12] = make_float4(o[12], o[13], o[14], o[15]);
        *(float2*)&d[16] = make_float2(ssA, ssB);
    }
    __syncthreads();
    if (g4 < 2) {
        const float* d = &stbuf[((g4 * 2 + hp) * 64 + lane) * 20];
        const float4 r0 = *(const float4*)&d[0];
        const float4 r1 = *(const float4*)&d[4];
        const float4 r2 = *(const float4*)&d[8];
        const float4 r3 = *(const float4*)&d[12];
        const float2 rs = *(const float2*)&d[16];
        o[0] += r0.x; o[1] += r0.y; o[2]  += r0.z; o[3]  += r0.w;
        o[4] += r1.x; o[5] += r1.y; o[6]  += r1.z; o[7]  += r1.w;
        o[8] += r2.x; o[9] += r2.y; o[10] += r2.z; o[11] += r2.w;
        o[12] += r3.x; o[13] += r3.y; o[14] += r3.z; o[15] += r3.w;
        ssA += rs.x; ssB += rs.y;
    }
    __syncthreads();
    if (g4 == 1) {
        float* d = &stbuf[(hp * 64 + lane) * 20];
        *(float4*)&d[0]  = make_float4(o[0],  o[1],  o[2],  o[3]);
        *(float4*)&d[4]  = make_float4(o[4],  o[5],  o[6],  o[7]);
        *(float4*)&d[8]  = make_float4(o[8],  o[9],  o[10], o[11]);
        *(float4*)&d[12] = make_float4(o[12], o[13], o[14], o[15]);
        *(float2*)&d[16] = make_float2(ssA, ssB);
    }
    __syncthreads();
    if (g4 == 0) {
        const float* d = &stbuf[(hp * 64 + lane) * 20];
        const float4 r0 = *(const float4*)&d[0];
        const float4 r1 = *(const float4*)&d[4];
        const float4 r2 = *(const float4*)&d[8];
        const float4 r3 = *(const float4*)&d[12];
        const float2 rs = *(const float2*)&d[16];
        o[0] += r0.x; o[1] += r0.y; o[2]  += r0.z; o[3]  += r0.w;
        o[4] += r1.x; o[5] += r1.y; o[6]  += r1.z; o[7]  += r1.w;
        o[8] += r2.x; o[9] += r2.y; o[10] += r2.z; o[11] += r2.w;
        o[12] += r3.x; o[13] += r3.y; o[14] += r3.z; o[15] += r3.w;
        ssA += rs.x; ssB += rs.y;
        const float invA = 1.0f / ssA;
        const float invB = 1.0f / ssB;
        #pragma unroll
        for (int r = 0; r < 8; ++r)  o[r] *= invA;
        #pragma unroll
        for (int r = 8; r < 16; ++r) o[r] *= invB;
    }

    // ---- epilogue (g4==0 waves cover all 64 channels x 32 cols) ----
    const int n = nb * 16 + e;
    if (FIRST) {
        if (g4 == 0) {
            const int cell = (n * 32 + a) * 32 + bb0 + ci;
            const float xn0 = (x[cell*3+0] - mean0) * rs0;
            const float xn1 = (x[cell*3+1] - mean1) * rs1;
            const float xn2 = (x[cell*3+2] - mean2) * rs2;
            #pragma unroll
            for (int g = 0; g < 4; ++g) {
                short4 hb4; short* hbp = (short*)&hb4;
                #pragma unroll
                for (int i = 0; i < 4; ++i) {
                    const int c = hp * 32 + g * 8 + 4 * h5 + i;
                    const float res = Waux[192+c] + xn0*Waux[c] + xn1*Waux[64+c] + xn2*Waux[128+c];
                    hbp[i] = f2bs(o[g * 4 + i] + res);
                }
                *(short4*)&hbf_out[cell * 64 + hp * 32 + g * 8 + 4 * h5] = hb4;
            }
        }
    } else {
        __syncthreads();                   // stbuf reads done; reuse LDS for hf
        float* hf = (float*)HnS;           // [32 cols][pitch 68]
        if (g4 == 0) {
            const int cell = (n * 32 + a) * 32 + bb0 + ci;
            #pragma unroll
            for (int g = 0; g < 4; ++g) {
                const short4 hb4 = *(const short4*)&hbf_in[cell * 64 + hp * 32 + g * 8 + 4 * h5];
                float4 tv = make_float4(o[g*4+0] + bs2f(hb4.x), o[g*4+1] + bs2f(hb4.y),
                                        o[g*4+2] + bs2f(hb4.z), o[g*4+3] + bs2f(hb4.w));
                *(float4*)&hf[col * 68 + hp * 32 + g * 8 + 4 * h5] = tv;
            }
        }
        __syncthreads();
        // out-proj: 96 outputs x 4 partial-threads (16 channels each) + shfl reduce
        if (tid < 384) {
            const int oid = tid >> 2, part = tid & 3;
            const int rowglob = oid / 3, f = oid - rowglob * 3;
            const int cstart = part << 4;
            float acc = 0.f;
            #pragma unroll
            for (int cc = 0; cc < 16; ++cc)
                acc += hf[rowglob * 68 + cstart + cc] * Waux[(cstart + cc) * 3 + f];
            acc += __shfl_xor(acc, 1);
            acc += __shfl_xor(acc, 2);
            if (part == 0) {
                const int cio = rowglob >> 4, row = rowglob & 15;
                out[(((nb * 16 + row) * 32 + a) * 32 + bb0 + cio) * 3 + f] =
                    acc + Waux[192 + f];
            }
        }
    }
}

extern "C" void kernel_launch(void* const* d_in, const int* in_sizes, int n_in,
                              void* d_out, int out_size, void* d_ws, size_t ws_size,
                              hipStream_t stream) {
    const float* x     = (const float*)d_in[0];
    const float* W_in  = (const float*)d_in[1];
    const float* b_in  = (const float*)d_in[2];
    const float* W_out = (const float*)d_in[3];
    const float* b_out = (const float*)d_in[4];
    const float* Wq    = (const float*)d_in[5];
    const float* bq    = (const float*)d_in[6];
    const float* Wk    = (const float*)d_in[7];
    const float* bk    = (const float*)d_in[8];
    const float* Wv    = (const float*)d_in[9];
    const float* bv    = (const float*)d_in[10];

    float* ws    = (float*)d_ws;
    float* sums  = ws;                          // 32 x 8 floats (BN partials)
    short* h1bf  = (short*)(ws + 256);          // 2M shorts (4 MB)
    short* wB    = h1bf + 2097152;              // 110 x 4096 bf16 (0.9 MB)
    float* out   = (float*)d_out;

    prep_kernel<<<142, 256, 0, stream>>>(Wq, Wk, Wv, wB, x, sums);

    const short* wq0 = wB;                const short* wq1 = wB + 4096;
    const short* wk0 = wB + 2 * 4096;     const short* wk1 = wB + (2 + 27) * 4096;
    const short* wv0 = wB + 56 * 4096;    const short* wv1 = wB + (56 + 27) * 4096;

    dim3 grid(16, 32, 2);
    layer_fused<true><<<grid, 512, 0, stream>>>(
        x, sums, W_in, b_in, nullptr, h1bf, nullptr, nullptr, nullptr,
        wq0, bq, wk0, bk, wv0, bv);
    layer_fused<false><<<grid, 512, 0, stream>>>(
        nullptr, nullptr, nullptr, nullptr, h1bf, nullptr, W_out, b_out, out,
        wq1, bq + 64, wk1, bk + 1728, wv1, bv + 1728);
}

// Round 6
// 133.737 us; speedup vs baseline: 1.1462x; 1.1462x over previous
//
#include <hip/hip_runtime.h>
#include <hip/hip_bf16.h>

// N=32 time, 32x32 grid, C=64 (H=4 x D=16), 3x3x3 offsets (M=27), 2 layers.
// R17 = no-m-split restructure. R11-R16 all split m across waves -> 4x Q
// duplication + 4-barrier LDS merge tail + 7-iter wave loops; none of
// occupancy (R13), VALU count (R14), or prefetch depth (R15/R16) moved the
// ~41-44us layer time. R17: block = 4 waves (256t) x (hp, 2-cell colgroup),
// each wave loops ALL 27 m's, softmax entirely in registers:
//  - merge phase GONE (no barriers after staging for FIRST)
//  - Q computed once per wave (was 4x redundant)
//  - uniform counted 27-iter loop, branch-free, unroll-3
//  - grid (8,32,2)=512 blocks = 2 blocks/CU co-resident (LDS 56.4KB)
//  - same-hp waves hit same weight cachelines (L1 reuse)
// __launch_bounds__(256,2): 256-VGPR budget (R12 lesson: never force below
// need; spill tripwire = WRITE_SIZE >> 4MB).

typedef short short8_t __attribute__((ext_vector_type(8)));
typedef float floatx16 __attribute__((ext_vector_type(16)));

__device__ __forceinline__ short f2bs(float f) {
    __hip_bfloat16 h = __float2bfloat16(f);
    return *reinterpret_cast<short*>(&h);
}
__device__ __forceinline__ float bs2f(short s) {
    union { unsigned u; float f; } v;
    v.u = ((unsigned)(unsigned short)s) << 16;
    return v.f;
}
// swizzled halo addressing: rowid in [0,324), 8 chunks of 8 shorts, pitch 64
__device__ __forceinline__ int hn_idx(int rowid, int chunk) {
    return rowid * 64 + ((chunk ^ (rowid & 7)) << 3);
}
// p(lane) + p(lane^32), all lanes (VALU pipe, no DS)
__device__ __forceinline__ float half_sum(float p) {
    float a = p, b = p;
    asm("v_permlane32_swap_b32 %0, %1" : "+v"(a), "+v"(b));
    return a + b;
}

// ---------------- prep: repack weights (coalesced) + BN partial sums ----------------
// blocks 0..109: one matrix each. 110..141: BN partial sums.
__global__ void prep_kernel(const float* __restrict__ Wq, const float* __restrict__ Wk,
                            const float* __restrict__ Wv, short* __restrict__ dst,
                            const float* __restrict__ x, float* __restrict__ sums) {
    if (blockIdx.x < 110) {
        __shared__ float Wf[4096];
        const int mat = blockIdx.x;
        const float* W;
        if (mat < 2)       W = Wq + mat * 4096;
        else if (mat < 56) W = Wk + (mat - 2) * 4096;
        else               W = Wv + (mat - 56) * 4096;
        const float4* W4 = (const float4*)W;
        #pragma unroll
        for (int i = 0; i < 4; ++i) {
            const int idx = threadIdx.x + i * 256;
            *(float4*)&Wf[idx * 4] = W4[idx];
        }
        __syncthreads();
        // out entry t2 = (hp*4+kk)*64 + lane; A[row=hp*32+(lane&31)][k] layout
        #pragma unroll
        for (int u = 0; u < 2; ++u) {
            const int t2 = u * 256 + threadIdx.x;
            const int hp = t2 >> 8, kk = (t2 >> 6) & 3, lane = t2 & 63;
            const int krow = kk * 16 + ((lane >> 5) << 3);
            const int col  = hp * 32 + (lane & 31);
            short8_t v;
            #pragma unroll
            for (int j = 0; j < 8; ++j) v[j] = f2bs(Wf[(krow + j) * 64 + col]);
            *(short8_t*)&dst[(size_t)mat * 4096 + t2 * 8] = v;
        }
    } else {
        int bid = blockIdx.x - 110;
        int t = bid * 256 + threadIdx.x;          // 8192 threads x 3 float4
        const float4* x4 = (const float4*)x;
        float4 v0 = x4[t * 3 + 0], v1 = x4[t * 3 + 1], v2 = x4[t * 3 + 2];
        float vv[6];
        vv[0] = v0.x + v0.w + v1.z + v2.y;
        vv[1] = v0.y + v1.x + v1.w + v2.z;
        vv[2] = v0.z + v1.y + v2.x + v2.w;
        vv[3] = v0.x*v0.x + v0.w*v0.w + v1.z*v1.z + v2.y*v2.y;
        vv[4] = v0.y*v0.y + v1.x*v1.x + v1.w*v1.w + v2.z*v2.z;
        vv[5] = v0.z*v0.z + v1.y*v1.y + v2.x*v2.x + v2.w*v2.w;
        #pragma unroll
        for (int i = 0; i < 6; ++i) {
            #pragma unroll
            for (int off = 1; off < 64; off <<= 1) vv[i] += __shfl_xor(vv[i], off);
        }
        __shared__ float part[4][6];
        if ((threadIdx.x & 63) == 0) {
            #pragma unroll
            for (int i = 0; i < 6; ++i) part[threadIdx.x >> 6][i] = vv[i];
        }
        __syncthreads();
        if (threadIdx.x < 6)
            sums[bid * 8 + threadIdx.x] = part[0][threadIdx.x] + part[1][threadIdx.x] +
                                          part[2][threadIdx.x] + part[3][threadIdx.x];
    }
}

// ---------------- fused attention layer ----------------
// grid (bx=8, a=32, nb=2); block 256 = 4 waves; wave = cg*2 + hp;
// hp = headpair (channels hp*32..+31); cg = colgroup (cells bb0+cg*2, +1).
// lane: col = lane&31 -> (ci = col>>4 cell-in-group, e = col&15 time row);
// h5 = lane>>5. Each wave: all 27 m's, softmax in registers, no merge.
template <bool FIRST>
__global__ __launch_bounds__(256, 2)
void layer_fused(const float* __restrict__ x, const float* __restrict__ sums,
                 const float* __restrict__ W_in, const float* __restrict__ b_in,
                 const short* __restrict__ hbf_in, short* __restrict__ hbf_out,
                 const float* __restrict__ Wout, const float* __restrict__ bout,
                 float* __restrict__ out,
                 const short* __restrict__ wqB, const float* __restrict__ bq,
                 const short* __restrict__ wkB, const float* __restrict__ bk,
                 const short* __restrict__ wvB, const float* __restrict__ bv) {
    __shared__ short HnS[324 * 64];   // 41.5 KB halo; reused for hf (SECOND)
    __shared__ float BiasS[3456];     // 13.8 KB: [m][k|v][64ch]
    __shared__ float Waux[256];
    __shared__ float bn6[6];

    const int tid = threadIdx.x;
    const int bb0 = blockIdx.x * 4, a = blockIdx.y, nb = blockIdx.z;

    if (FIRST) {
        if (tid < 3) {
            float s = 0.f, qq = 0.f;
            #pragma unroll
            for (int p = 0; p < 32; ++p) { s += sums[p * 8 + tid]; qq += sums[p * 8 + 3 + tid]; }
            float mean = s * (1.f / 32768.f);
            float var  = qq * (1.f / 32768.f) - mean * mean;
            bn6[tid]     = mean;
            bn6[3 + tid] = rsqrtf(var + 1e-5f);
        }
        if (tid < 192) Waux[tid] = W_in[tid];
        else           Waux[tid] = b_in[tid - 192];
    } else {
        if (tid < 192)      Waux[tid] = Wout[tid];
        else if (tid < 195) Waux[tid] = bout[tid - 192];
    }
    __syncthreads();

    float mean0 = 0, mean1 = 0, mean2 = 0, rs0 = 0, rs1 = 0, rs2 = 0;
    if (FIRST) {
        mean0 = bn6[0]; mean1 = bn6[1]; mean2 = bn6[2];
        rs0 = bn6[3]; rs1 = bn6[4]; rs2 = bn6[5];
    }

    // ---- stage biases: BiasS[m*128 + (k?0:64) + ch] ----
    for (int id = tid; id < 3456; id += 256) {
        const int half = (id >= 1728) ? 1 : 0;
        const int j = id - half * 1728;
        const float* src = half ? &bv[j] : &bk[j];
        BiasS[((j >> 6) << 7) + (half << 6) + (j & 63)] = *src;
    }

    // ---- stage halo: 324 rows x 8 chunks of 8 bf16 ----
    // rowid = rw*18 + r; rw = spa*6 + jcol (3 spa x 6 jcol), r = time row
    for (int id = tid; id < 2592; id += 256) {
        int rowid = id >> 3, cc = id & 7;
        int r = rowid % 18;
        int rw = rowid / 18;
        int spa = rw / 6, jcol = rw - spa * 6;
        int aa = a + spa - 1, bb = bb0 + jcol - 1;
        int n  = nb * 16 + r - 1;
        short8_t v = {0, 0, 0, 0, 0, 0, 0, 0};
        if ((unsigned)n < 32u && (unsigned)aa < 32u && (unsigned)bb < 32u) {
            int cell = (n * 32 + aa) * 32 + bb;
            if (FIRST) {
                float xn0 = (x[cell*3+0] - mean0) * rs0;
                float xn1 = (x[cell*3+1] - mean1) * rs1;
                float xn2 = (x[cell*3+2] - mean2) * rs2;
                #pragma unroll
                for (int j = 0; j < 8; ++j) {
                    int c = cc * 8 + j;
                    float h = Waux[192+c] + xn0*Waux[c] + xn1*Waux[64+c] + xn2*Waux[128+c];
                    v[j] = f2bs(h);
                }
            } else {
                v = *(const short8_t*)&hbf_in[cell * 64 + cc * 8];
            }
        }
        *(short8_t*)&HnS[hn_idx(rowid, cc)] = v;
    }
    __syncthreads();

    const int lane = tid & 63;
    const int wv4  = tid >> 6;
    const int hp   = wv4 & 1;        // headpair
    const int cg   = wv4 >> 1;       // colgroup (2 cells)
    const int col  = lane & 31;
    const int e    = col & 15;
    const int ci   = col >> 4;
    const int h5   = lane >> 5;
    const int cell4 = cg * 2 + ci;   // cell index within block, 0..3
    const int bcell = bb0 + cell4;   // absolute b of this lane's cell

    // validity masks
    unsigned amask = 0;
    #pragma unroll
    for (int d = 0; d < 3; ++d) if ((unsigned)(a + d - 1) < 32u) amask |= 1u << d;
    unsigned vmask = 0;
    #pragma unroll
    for (int j = 0; j < 3; ++j) if ((unsigned)(bcell + j - 1) < 32u) vmask |= 1u << j;

    const int elane = cell4 * 18 + e;   // per-lane halo-row offset

    // ---- Q projection (center: spa=1 -> rw = 6 + cell4 + 1): 4 MFMAs ----
    floatx16 qv;
    {
        const float* bqp = &bq[hp * 32 + 4 * h5];
        const float4 qa = *(const float4*)&bqp[0];
        const float4 qb = *(const float4*)&bqp[8];
        const float4 qc = *(const float4*)&bqp[16];
        const float4 qd = *(const float4*)&bqp[24];
        qv = floatx16{qa.x,qa.y,qa.z,qa.w, qb.x,qb.y,qb.z,qb.w,
                      qc.x,qc.y,qc.z,qc.w, qd.x,qd.y,qd.z,qd.w};
        const int hrow = (7 + cell4) * 18 + e + 1;
        const int hb = hrow * 64, xr = hrow & 7;
        const short8_t b0 = *(const short8_t*)&HnS[hb + (((0 + h5) ^ xr) << 3)];
        const short8_t b1 = *(const short8_t*)&HnS[hb + (((2 + h5) ^ xr) << 3)];
        const short8_t b2 = *(const short8_t*)&HnS[hb + (((4 + h5) ^ xr) << 3)];
        const short8_t b3 = *(const short8_t*)&HnS[hb + (((6 + h5) ^ xr) << 3)];
        const short8_t* wqp = (const short8_t*)&wqB[(hp * 256 + lane) * 8];
        qv = __builtin_amdgcn_mfma_f32_32x32x16_bf16(wqp[0],   b0, qv, 0, 0, 0);
        qv = __builtin_amdgcn_mfma_f32_32x32x16_bf16(wqp[64],  b1, qv, 0, 0, 0);
        qv = __builtin_amdgcn_mfma_f32_32x32x16_bf16(wqp[128], b2, qv, 0, 0, 0);
        qv = __builtin_amdgcn_mfma_f32_32x32x16_bf16(wqp[192], b3, qv, 0, 0, 0);
    }

    // ---- fused K/V pass: ALL 27 m's per wave, branch-free ----
    floatx16 o = {0,0,0,0, 0,0,0,0, 0,0,0,0, 0,0,0,0};
    float ssA = 0.f, ssB = 0.f;

    const short* wkBase = wkB + hp * 2048 + lane * 8;
    const short* wvBase = wvB + hp * 2048 + lane * 8;

    #pragma unroll 3
    for (int m = 0; m < 27; ++m) {
        const int t  = (m * 57) >> 9;          // m/9 for m<27
        const int sp = m - 9 * t;
        const int di = (sp * 11) >> 5;         // sp/3 for sp<9
        const int dj = sp - 3 * di;

        const int hrow = di * 108 + dj * 18 + t + elane;
        const int hb = hrow * 64, xr = hrow & 7;
        const short8_t b0 = *(const short8_t*)&HnS[hb + (((0 + h5) ^ xr) << 3)];
        const short8_t b1 = *(const short8_t*)&HnS[hb + (((2 + h5) ^ xr) << 3)];
        const short8_t b2 = *(const short8_t*)&HnS[hb + (((4 + h5) ^ xr) << 3)];
        const short8_t b3 = *(const short8_t*)&HnS[hb + (((6 + h5) ^ xr) << 3)];

        const float* bks = &BiasS[(m << 7) + (hp << 5) + (h5 << 2)];
        const float4 ka = *(const float4*)&bks[0];
        const float4 kb = *(const float4*)&bks[8];
        const float4 kc = *(const float4*)&bks[16];
        const float4 kd = *(const float4*)&bks[24];
        const float4 va0 = *(const float4*)&bks[64];
        const float4 va1 = *(const float4*)&bks[72];
        const float4 va2 = *(const float4*)&bks[80];
        const float4 va3 = *(const float4*)&bks[88];

        const short8_t wk0 = *(const short8_t*)&wkBase[m * 4096 + 0];
        const short8_t wk1 = *(const short8_t*)&wkBase[m * 4096 + 512];
        const short8_t wk2 = *(const short8_t*)&wkBase[m * 4096 + 1024];
        const short8_t wk3 = *(const short8_t*)&wkBase[m * 4096 + 1536];
        const short8_t wv0 = *(const short8_t*)&wvBase[m * 4096 + 0];
        const short8_t wv1 = *(const short8_t*)&wvBase[m * 4096 + 512];
        const short8_t wv2 = *(const short8_t*)&wvBase[m * 4096 + 1024];
        const short8_t wv3 = *(const short8_t*)&wvBase[m * 4096 + 1536];

        floatx16 kacc = floatx16{ka.x,ka.y,ka.z,ka.w, kb.x,kb.y,kb.z,kb.w,
                                 kc.x,kc.y,kc.z,kc.w, kd.x,kd.y,kd.z,kd.w};
        kacc = __builtin_amdgcn_mfma_f32_32x32x16_bf16(wk0, b0, kacc, 0, 0, 0);
        kacc = __builtin_amdgcn_mfma_f32_32x32x16_bf16(wk1, b1, kacc, 0, 0, 0);
        kacc = __builtin_amdgcn_mfma_f32_32x32x16_bf16(wk2, b2, kacc, 0, 0, 0);
        kacc = __builtin_amdgcn_mfma_f32_32x32x16_bf16(wk3, b3, kacc, 0, 0, 0);

        floatx16 vacc = floatx16{va0.x,va0.y,va0.z,va0.w, va1.x,va1.y,va1.z,va1.w,
                                 va2.x,va2.y,va2.z,va2.w, va3.x,va3.y,va3.z,va3.w};
        vacc = __builtin_amdgcn_mfma_f32_32x32x16_bf16(wv0, b0, vacc, 0, 0, 0);
        vacc = __builtin_amdgcn_mfma_f32_32x32x16_bf16(wv1, b1, vacc, 0, 0, 0);
        vacc = __builtin_amdgcn_mfma_f32_32x32x16_bf16(wv2, b2, vacc, 0, 0, 0);
        vacc = __builtin_amdgcn_mfma_f32_32x32x16_bf16(wv3, b3, vacc, 0, 0, 0);

        // score: head A = regs 0..7, head B = regs 8..15 (+ partner lane half)
        float pA = kacc[0] * qv[0];
        #pragma unroll
        for (int r = 1; r < 8; ++r) pA += kacc[r] * qv[r];
        float pB = kacc[8] * qv[8];
        #pragma unroll
        for (int r = 9; r < 16; ++r) pB += kacc[r] * qv[r];
        pA = half_sum(pA);
        pB = half_sum(pB);
        const float mf = (float)(((amask >> di) & (vmask >> dj)) & 1u);
        const float wA = __expf(pA) * mf;
        const float wB = __expf(pB) * mf;
        ssA += wA; ssB += wB;
        #pragma unroll
        for (int r = 0; r < 8; ++r)  o[r] += wA * vacc[r];
        #pragma unroll
        for (int r = 8; r < 16; ++r) o[r] += wB * vacc[r];
    }

    // ---- normalize (complete softmax: this wave saw all 27 m's) ----
    {
        const float invA = 1.0f / ssA;
        const float invB = 1.0f / ssB;
        #pragma unroll
        for (int r = 0; r < 8; ++r)  o[r] *= invA;
        #pragma unroll
        for (int r = 8; r < 16; ++r) o[r] *= invB;
    }

    // ---- epilogue ----
    const int n = nb * 16 + e;
    const int cell = (n * 32 + a) * 32 + bcell;
    if (FIRST) {
        const float xn0 = (x[cell*3+0] - mean0) * rs0;
        const float xn1 = (x[cell*3+1] - mean1) * rs1;
        const float xn2 = (x[cell*3+2] - mean2) * rs2;
        #pragma unroll
        for (int g = 0; g < 4; ++g) {
            short4 hb4; short* hbp = (short*)&hb4;
            #pragma unroll
            for (int i = 0; i < 4; ++i) {
                const int c = hp * 32 + g * 8 + 4 * h5 + i;
                const float res = Waux[192+c] + xn0*Waux[c] + xn1*Waux[64+c] + xn2*Waux[128+c];
                hbp[i] = f2bs(o[g * 4 + i] + res);
            }
            *(short4*)&hbf_out[cell * 64 + hp * 32 + g * 8 + 4 * h5] = hb4;
        }
    } else {
        __syncthreads();                   // all halo reads done; reuse LDS for hf
        float* hf = (float*)HnS;           // [64 cols][pitch 68]
        const int bcol = cell4 * 16 + e;   // 0..63
        #pragma unroll
        for (int g = 0; g < 4; ++g) {
            const short4 hb4 = *(const short4*)&hbf_in[cell * 64 + hp * 32 + g * 8 + 4 * h5];
            float4 tv = make_float4(o[g*4+0] + bs2f(hb4.x), o[g*4+1] + bs2f(hb4.y),
                                    o[g*4+2] + bs2f(hb4.z), o[g*4+3] + bs2f(hb4.w));
            *(float4*)&hf[bcol * 68 + hp * 32 + g * 8 + 4 * h5] = tv;
        }
        __syncthreads();
        // out-proj: 192 outputs (64 cols x 3 features), 64-ch dot each
        if (tid < 192) {
            const int rowglob = tid / 3, f = tid - rowglob * 3;  // rowglob = bcol
            float acc = Waux[192 + f];
            #pragma unroll 8
            for (int cc = 0; cc < 64; ++cc) acc += hf[rowglob * 68 + cc] * Waux[cc * 3 + f];
            const int cellb = bb0 + (rowglob >> 4), row = rowglob & 15;
            out[(((nb * 16 + row) * 32 + a) * 32 + cellb) * 3 + f] = acc;
        }
    }
}

extern "C" void kernel_launch(void* const* d_in, const int* in_sizes, int n_in,
                              void* d_out, int out_size, void* d_ws, size_t ws_size,
                              hipStream_t stream) {
    const float* x     = (const float*)d_in[0];
    const float* W_in  = (const float*)d_in[1];
    const float* b_in  = (const float*)d_in[2];
    const float* W_out = (const float*)d_in[3];
    const float* b_out = (const float*)d_in[4];
    const float* Wq    = (const float*)d_in[5];
    const float* bq    = (const float*)d_in[6];
    const float* Wk    = (const float*)d_in[7];
    const float* bk    = (const float*)d_in[8];
    const float* Wv    = (const float*)d_in[9];
    const float* bv    = (const float*)d_in[10];

    float* ws    = (float*)d_ws;
    float* sums  = ws;                          // 32 x 8 floats (BN partials)
    short* h1bf  = (short*)(ws + 256);          // 2M shorts (4 MB)
    short* wB    = h1bf + 2097152;              // 110 x 4096 bf16 (0.9 MB)
    float* out   = (float*)d_out;

    prep_kernel<<<142, 256, 0, stream>>>(Wq, Wk, Wv, wB, x, sums);

    const short* wq0 = wB;                const short* wq1 = wB + 4096;
    const short* wk0 = wB + 2 * 4096;     const short* wk1 = wB + (2 + 27) * 4096;
    const short* wv0 = wB + 56 * 4096;    const short* wv1 = wB + (56 + 27) * 4096;

    dim3 grid(8, 32, 2);
    layer_fused<true><<<grid, 256, 0, stream>>>(
        x, sums, W_in, b_in, nullptr, h1bf, nullptr, nullptr, nullptr,
        wq0, bq, wk0, bk, wv0, bv);
    layer_fused<false><<<grid, 256, 0, stream>>>(
        nullptr, nullptr, nullptr, nullptr, h1bf, nullptr, W_out, b_out, out,
        wq1, bq + 64, wk1, bk + 1728, wv1, bv + 1728);
}